// Round 7
// baseline (515.692 us; speedup 1.0000x reference)
//
#include <hip/hip_runtime.h>
#include <hip/hip_bf16.h>

#define N_NODES 100000
#define N_EDGES 1600000
#define BCAP    64          // bucket capacity per node (max degree; Poisson(16) tail ~1e-20)
#define EPS     1e-12f

typedef __bf16 bf16x8 __attribute__((ext_vector_type(8)));
typedef float  f32x4  __attribute__((ext_vector_type(4)));

__device__ __forceinline__ unsigned short f2bf(float f){
    union { float f; unsigned int i; } v; v.f = f;
    unsigned int x = v.i;
    return (unsigned short)((x + 0x7fffu + ((x >> 16) & 1u)) >> 16);
}
__device__ __forceinline__ float bits2f(unsigned int u){
    union { unsigned int i; float f; } v; v.i = u; return v.f;
}

// ---- K_init: blocks [0,390] zero deg; [391,646] fuse M/dvec; [647,662] W1 tile
__global__ void k_init(int* __restrict__ deg,
                       const float* __restrict__ lin_W,
                       const float* __restrict__ lin_b,
                       const float* __restrict__ conv_W,
                       __bf16* __restrict__ Mbf,
                       float* __restrict__ dvec,
                       const float* __restrict__ asg_W1,
                       __bf16* __restrict__ W1bf){
    int b = blockIdx.x;
    int t = threadIdx.x;
    if (b < 391){
        int i = b * 256 + t;
        if (i < N_NODES) deg[i] = 0;
    } else if (b < 647){
        int id = (b - 391) * 256 + t;             // 0..65535
        int f  = id & 255;
        int o  = id >> 8;                          // k*64+q
        int k  = o >> 6;
        const float* cw = conv_W + o * 64;         // conv_W[k][q][p]
        const float* lw = lin_W + k * 64 * 256 + f;// lin_W[k][p][f]
        float s = 0.f;
        #pragma unroll 8
        for (int p = 0; p < 64; ++p) s += cw[p] * lw[p * 256];
        Mbf[id] = (__bf16)s;
        if (f == 0){
            const float* lb = lin_b + k * 64;
            float d = 0.f;
            for (int p = 0; p < 64; ++p) d += lb[p] * cw[p];
            dvec[o] = d;
        }
    } else {
        int id = (b - 647) * 256 + t;              // 0..4095
        int f  = id & 255;
        int o  = id >> 8;                          // 0..15
        float v = 0.f;
        if (o < 4)      v = asg_W1[o * 512 + f];
        else if (o < 8) v = asg_W1[(o - 4) * 512 + 256 + f];
        W1bf[id] = (__bf16)v;
    }
}

// ---- K_gemm v3: 4 N-split waves over SAME 32 nodes; wave = 32 nodes x 64 outs.
// acc 32+8 regs; __launch_bounds__(256,4) pins 4 waves/SIMD; depth-1 register
// pipeline on the x loads (prefetch k0+32 before MFMAs of k0).
__global__ __launch_bounds__(256, 4) void k_gemm(const float* __restrict__ x,
                                              const __bf16* __restrict__ Mbf,
                                              const __bf16* __restrict__ W1bf,
                                              const float* __restrict__ dvec,
                                              __bf16* __restrict__ c,
                                              float* __restrict__ proj_a,
                                              float* __restrict__ proj_b){
    int lane = threadIdx.x & 63, wv = threadIdx.x >> 6;
    int nb = blockIdx.x * 32;              // 32 nodes per block (all waves share)
    int ob = wv * 64;                      // 64-out slice per wave
    int l15 = lane & 15, quad = lane >> 4;
    f32x4 acc[2][4], accp[2];
    #pragma unroll
    for (int mi = 0; mi < 2; ++mi){
        accp[mi] = f32x4{0.f, 0.f, 0.f, 0.f};
        #pragma unroll
        for (int ni = 0; ni < 4; ++ni) acc[mi][ni] = f32x4{0.f, 0.f, 0.f, 0.f};
    }
    const float* xg[2];
    #pragma unroll
    for (int mi = 0; mi < 2; ++mi){
        int row = nb + mi * 16 + l15;
        if (row >= N_NODES) row = N_NODES - 1;   // clamp for tail
        xg[mi] = x + (size_t)row * 256 + quad * 8;
    }
    // prime the pipeline: k0 = 0 raw fragments
    float4 cl[2], ch[2];
    #pragma unroll
    for (int mi = 0; mi < 2; ++mi){
        cl[mi] = *(const float4*)(xg[mi]);
        ch[mi] = *(const float4*)(xg[mi] + 4);
    }
    for (int k0 = 0; k0 < 256; k0 += 32){
        float4 nl[2], nh[2];
        bool pf = (k0 < 224);              // uniform branch; no OOB on last row
        if (pf){
            #pragma unroll
            for (int mi = 0; mi < 2; ++mi){
                nl[mi] = *(const float4*)(xg[mi] + k0 + 32);
                nh[mi] = *(const float4*)(xg[mi] + k0 + 36);
            }
        }
        bf16x8 a[2];
        #pragma unroll
        for (int mi = 0; mi < 2; ++mi){
            a[mi][0] = (__bf16)cl[mi].x; a[mi][1] = (__bf16)cl[mi].y;
            a[mi][2] = (__bf16)cl[mi].z; a[mi][3] = (__bf16)cl[mi].w;
            a[mi][4] = (__bf16)ch[mi].x; a[mi][5] = (__bf16)ch[mi].y;
            a[mi][6] = (__bf16)ch[mi].z; a[mi][7] = (__bf16)ch[mi].w;
        }
        #pragma unroll
        for (int ni = 0; ni < 4; ++ni){
            bf16x8 b = *(const bf16x8*)(Mbf + (size_t)(ob + ni * 16 + l15) * 256 + k0 + quad * 8);
            acc[0][ni] = __builtin_amdgcn_mfma_f32_16x16x32_bf16(a[0], b, acc[0][ni], 0, 0, 0);
            acc[1][ni] = __builtin_amdgcn_mfma_f32_16x16x32_bf16(a[1], b, acc[1][ni], 0, 0, 0);
        }
        if (wv == 0){
            bf16x8 bw = *(const bf16x8*)(W1bf + (size_t)l15 * 256 + k0 + quad * 8);
            accp[0] = __builtin_amdgcn_mfma_f32_16x16x32_bf16(a[0], bw, accp[0], 0, 0, 0);
            accp[1] = __builtin_amdgcn_mfma_f32_16x16x32_bf16(a[1], bw, accp[1], 0, 0, 0);
        }
        if (pf){
            #pragma unroll
            for (int mi = 0; mi < 2; ++mi){ cl[mi] = nl[mi]; ch[mi] = nh[mi]; }
        }
    }
    #pragma unroll
    for (int ni = 0; ni < 4; ++ni){
        int o = ob + ni * 16 + l15;
        float dv = dvec[o];
        #pragma unroll
        for (int mi = 0; mi < 2; ++mi){
            int nrow = nb + mi * 16 + quad * 4;
            #pragma unroll
            for (int r = 0; r < 4; ++r){
                int node = nrow + r;
                if (node < N_NODES) c[(size_t)node * 256 + o] = (__bf16)(acc[mi][ni][r] + dv);
            }
        }
    }
    if (wv == 0 && l15 < 8){
        #pragma unroll
        for (int mi = 0; mi < 2; ++mi){
            int nrow = nb + mi * 16 + quad * 4;
            #pragma unroll
            for (int r = 0; r < 4; ++r){
                int node = nrow + r;
                if (node < N_NODES){
                    float v = accp[mi][r];
                    if (l15 < 4) proj_a[node * 4 + l15] = v;
                    else         proj_b[node * 4 + (l15 - 4)] = v;
                }
            }
        }
    }
}

// ---- K_edge: local dtype detect + softmax gate + bucket scatter {col, w*4 bf16}
__global__ __launch_bounds__(256) void k_edge(const void* __restrict__ row_raw,
                                              const void* __restrict__ col_raw,
                                              const float* __restrict__ proj_a,
                                              const float* __restrict__ proj_b,
                                              const float* __restrict__ asg_b1,
                                              const float* __restrict__ asg_W2,
                                              const float* __restrict__ asg_b2,
                                              int* __restrict__ deg,
                                              int4* __restrict__ bucket){
    __shared__ int s_is64;
    int t = threadIdx.x;
    if (t == 0) s_is64 = 1;
    __syncthreads();
    // sample the first 512 words of both arrays: int64 inputs have all odd words 0
    unsigned v = ((const unsigned*)row_raw)[2 * t + 1] | ((const unsigned*)col_raw)[2 * t + 1];
    if (v) s_is64 = 0;
    __syncthreads();

    int e = blockIdx.x * 256 + t;
    if (e >= N_EDGES) return;
    int r, cl;
    if (s_is64){
        r  = (int)((const long long*)row_raw)[e];
        cl = (int)((const long long*)col_raw)[e];
    } else {
        r  = ((const int*)row_raw)[e];
        cl = ((const int*)col_raw)[e];
    }
    float4 pa = *(const float4*)(proj_a + (size_t)cl * 4);
    float4 pb = *(const float4*)(proj_b + (size_t)r * 4);
    float h1[4];
    h1[0] = pa.x + pb.x + asg_b1[0];
    h1[1] = pa.y + pb.y + asg_b1[1];
    h1[2] = pa.z + pb.z + asg_b1[2];
    h1[3] = pa.w + pb.w + asg_b1[3];
    float h2[4];
    #pragma unroll
    for (int i = 0; i < 4; ++i){
        float s = asg_b2[i];
        #pragma unroll
        for (int j = 0; j < 4; ++j) s += asg_W2[i * 4 + j] * h1[j];
        h2[i] = s;
    }
    float m = fmaxf(fmaxf(h2[0], h2[1]), fmaxf(h2[2], h2[3]));
    float e0 = __expf(h2[0] - m), e1 = __expf(h2[1] - m);
    float e2 = __expf(h2[2] - m), e3 = __expf(h2[3] - m);
    float inv = 1.f / (e0 + e1 + e2 + e3);
    unsigned b0 = f2bf(e0 * inv), b1 = f2bf(e1 * inv);
    unsigned b2 = f2bf(e2 * inv), b3 = f2bf(e3 * inv);
    int4 rec;
    rec.x = cl;
    rec.y = (int)(b0 | (b1 << 16));
    rec.z = (int)(b2 | (b3 << 16));
    rec.w = 0;
    int pos = atomicAdd(&deg[r], 1);
    if (pos < BCAP) bucket[(size_t)r * BCAP + pos] = rec;
}

// ---- K_node v2: ONE WAVE PER NODE. Zero barriers, zero LDS.
__global__ __launch_bounds__(256) void k_node(const __bf16* __restrict__ c,
                                              const int* __restrict__ deg,
                                              const int4* __restrict__ bucket,
                                              const float* __restrict__ bias,
                                              const float* __restrict__ cls_W,
                                              const float* __restrict__ cls_b,
                                              float* __restrict__ out_h,
                                              float* __restrict__ out_logits){
    int wv = __builtin_amdgcn_readfirstlane((int)(threadIdx.x >> 6));
    int l  = threadIdx.x & 63;
    int n  = blockIdx.x * 4 + wv;
    int k2 = l >> 4;

    // per-lane constants (L1/L2-resident)
    float4 bi = *(const float4*)(bias  + l * 4);
    float4 w0 = *(const float4*)(cls_W + 0 * 256 + l * 4);
    float4 w1 = *(const float4*)(cls_W + 1 * 256 + l * 4);
    float4 w2 = *(const float4*)(cls_W + 2 * 256 + l * 4);
    float4 w3 = *(const float4*)(cls_W + 3 * 256 + l * 4);

    int dn = deg[n]; if (dn > BCAP) dn = BCAP;
    const int4* rec = bucket + (size_t)n * BCAP;
    const __bf16* cb = c + (size_t)l * 4;

    bool hi2 = (k2 & 2) != 0;    // use rec.z (k=2,3) vs rec.y (k=0,1)
    bool odd = (k2 & 1) != 0;    // use hi16 vs lo16

    float a0 = 0.f, a1 = 0.f, a2 = 0.f, a3 = 0.f;
    #pragma unroll 4
    for (int i = 0; i < dn; ++i){
        int4 rc = rec[i];                         // wave-uniform -> s_load
        int  ww = hi2 ? rc.z : rc.y;
        unsigned wb = odd ? ((unsigned)ww & 0xffff0000u) : ((unsigned)ww << 16);
        float w = bits2f(wb);
        uint2 vv = *(const uint2*)(cb + (size_t)rc.x * 256);   // 8B/lane, 512B/wave
        a0 += w * bits2f(vv.x << 16);
        a1 += w * bits2f(vv.x & 0xffff0000u);
        a2 += w * bits2f(vv.y << 16);
        a3 += w * bits2f(vv.y & 0xffff0000u);
    }
    a0 += bi.x; a1 += bi.y; a2 += bi.z; a3 += bi.w;

    // norm over each 64-feature group = 16 consecutive lanes
    float ss = a0 * a0 + a1 * a1 + a2 * a2 + a3 * a3;
    ss += __shfl_xor(ss, 1);
    ss += __shfl_xor(ss, 2);
    ss += __shfl_xor(ss, 4);
    ss += __shfl_xor(ss, 8);
    float nrm = fmaxf(sqrtf(ss), EPS);
    float h0 = a0 / nrm, h1 = a1 / nrm, h2 = a2 / nrm, h3 = a3 / nrm;
    *(float4*)(out_h + (size_t)n * 256 + l * 4) = make_float4(h0, h1, h2, h3);

    // logits: per-lane partial dot then full-wave butterfly
    float p0 = h0 * w0.x + h1 * w0.y + h2 * w0.z + h3 * w0.w;
    float p1 = h0 * w1.x + h1 * w1.y + h2 * w1.z + h3 * w1.w;
    float p2 = h0 * w2.x + h1 * w2.y + h2 * w2.z + h3 * w2.w;
    float p3 = h0 * w3.x + h1 * w3.y + h2 * w3.z + h3 * w3.w;
    #pragma unroll
    for (int off = 1; off < 64; off <<= 1){
        p0 += __shfl_xor(p0, off);
        p1 += __shfl_xor(p1, off);
        p2 += __shfl_xor(p2, off);
        p3 += __shfl_xor(p3, off);
    }
    if (l == 0){
        float4 lg = make_float4(p0 + cls_b[0], p1 + cls_b[1],
                                p2 + cls_b[2], p3 + cls_b[3]);
        *(float4*)(out_logits + (size_t)n * 4) = lg;
    }
}

extern "C" void kernel_launch(void* const* d_in, const int* in_sizes, int n_in,
                              void* d_out, int out_size, void* d_ws, size_t ws_size,
                              hipStream_t stream){
    const float* x       = (const float*)d_in[0];
    const void*  row_raw = d_in[1];
    const void*  col_raw = d_in[2];
    const float* asg_W1  = (const float*)d_in[3];
    const float* asg_b1  = (const float*)d_in[4];
    const float* asg_W2  = (const float*)d_in[5];
    const float* asg_b2  = (const float*)d_in[6];
    const float* lin_W   = (const float*)d_in[7];
    const float* lin_b   = (const float*)d_in[8];
    const float* conv_W  = (const float*)d_in[9];
    const float* bias    = (const float*)d_in[10];
    const float* cls_W   = (const float*)d_in[11];
    const float* cls_b   = (const float*)d_in[12];

    char* ws = (char*)d_ws;
    size_t off = 0;
    auto alloc = [&](size_t bytes) -> void* {
        void* p = ws + off;
        off += (bytes + 255) & ~(size_t)255;
        return p;
    };
    __bf16* c      = (__bf16*)alloc((size_t)N_NODES * 256 * 2);       // 51.2 MB
    int4*   bucket = (int4*)alloc((size_t)N_NODES * BCAP * 16);       // 102.4 MB
    float*  proj_a = (float*)alloc((size_t)N_NODES * 4 * 4);
    float*  proj_b = (float*)alloc((size_t)N_NODES * 4 * 4);
    __bf16* Mbf    = (__bf16*)alloc(65536 * 2);
    __bf16* W1bf   = (__bf16*)alloc(4096 * 2);
    float*  dvec   = (float*)alloc(256 * 4);
    int*    deg    = (int*)alloc((size_t)N_NODES * 4);

    float* out_h = (float*)d_out;
    float* out_l = out_h + (size_t)N_NODES * 256;

    hipLaunchKernelGGL(k_init, dim3(663), dim3(256), 0, stream,
                       deg, lin_W, lin_b, conv_W, Mbf, dvec, asg_W1, W1bf);
    hipLaunchKernelGGL(k_gemm, dim3((N_NODES + 31) / 32), dim3(256), 0, stream,
                       x, (const __bf16*)Mbf, (const __bf16*)W1bf, dvec, c, proj_a, proj_b);
    hipLaunchKernelGGL(k_edge, dim3(N_EDGES / 256), dim3(256), 0, stream,
                       row_raw, col_raw, proj_a, proj_b, asg_b1, asg_W2, asg_b2,
                       deg, bucket);
    hipLaunchKernelGGL(k_node, dim3(N_NODES / 4), dim3(256), 0, stream,
                       c, deg, bucket, bias, cls_W, cls_b, out_h, out_l);
}

// Round 8
// 506.304 us; speedup vs baseline: 1.0185x; 1.0185x over previous
//
#include <hip/hip_runtime.h>
#include <hip/hip_bf16.h>

#define N_NODES 100000
#define N_EDGES 1600000
#define BCAP    64          // bucket capacity per node (max degree; Poisson(16) tail ~1e-20)
#define EPS     1e-12f

typedef __bf16 bf16x8 __attribute__((ext_vector_type(8)));
typedef float  f32x4  __attribute__((ext_vector_type(4)));

__device__ __forceinline__ unsigned short f2bf(float f){
    union { float f; unsigned int i; } v; v.f = f;
    unsigned int x = v.i;
    return (unsigned short)((x + 0x7fffu + ((x >> 16) & 1u)) >> 16);
}
__device__ __forceinline__ float bits2f(unsigned int u){
    union { unsigned int i; float f; } v; v.i = u; return v.f;
}

// ---- K_init: [0,390] zero deg; [391,646] fuse M/dvec; [647,662] W1 tile;
//              [663,13162] xbf = bf16(x)  (feeds k_gemm; aliased over bucket)
__global__ void k_init(int* __restrict__ deg,
                       const float* __restrict__ lin_W,
                       const float* __restrict__ lin_b,
                       const float* __restrict__ conv_W,
                       __bf16* __restrict__ Mbf,
                       float* __restrict__ dvec,
                       const float* __restrict__ asg_W1,
                       __bf16* __restrict__ W1bf,
                       const float* __restrict__ x,
                       __bf16* __restrict__ xbf){
    int b = blockIdx.x;
    int t = threadIdx.x;
    if (b < 391){
        int i = b * 256 + t;
        if (i < N_NODES) deg[i] = 0;
    } else if (b < 647){
        int id = (b - 391) * 256 + t;             // 0..65535
        int f  = id & 255;
        int o  = id >> 8;                          // k*64+q
        int k  = o >> 6;
        const float* cw = conv_W + o * 64;         // conv_W[k][q][p]
        const float* lw = lin_W + k * 64 * 256 + f;// lin_W[k][p][f]
        float s = 0.f;
        #pragma unroll 8
        for (int p = 0; p < 64; ++p) s += cw[p] * lw[p * 256];
        Mbf[id] = (__bf16)s;
        if (f == 0){
            const float* lb = lin_b + k * 64;
            float d = 0.f;
            for (int p = 0; p < 64; ++p) d += lb[p] * cw[p];
            dvec[o] = d;
        }
    } else if (b < 663){
        int id = (b - 647) * 256 + t;              // 0..4095
        int f  = id & 255;
        int o  = id >> 8;                          // 0..15
        float v = 0.f;
        if (o < 4)      v = asg_W1[o * 512 + f];
        else if (o < 8) v = asg_W1[(o - 4) * 512 + 256 + f];
        W1bf[id] = (__bf16)v;
    } else {
        // bf16 conversion of x: 8 elems/thread, 12500 blocks x 2048 elems
        size_t e8 = ((size_t)(b - 663) * 256 + t) * 8;   // covers 25.6M exactly
        float4 lo = *(const float4*)(x + e8);
        float4 hi = *(const float4*)(x + e8 + 4);
        bf16x8 v;
        v[0] = (__bf16)lo.x; v[1] = (__bf16)lo.y; v[2] = (__bf16)lo.z; v[3] = (__bf16)lo.w;
        v[4] = (__bf16)hi.x; v[5] = (__bf16)hi.y; v[6] = (__bf16)hi.z; v[7] = (__bf16)hi.w;
        *(bf16x8*)(xbf + e8) = v;
    }
}

// ---- K_gemm v4: v2 geometry (2Mx2N waves, 64 nodes/block, wave = 32n x 128o)
// + direct bf16 A-loads from precomputed xbf (1 dwordx4/fragment, no cvt chain).
__global__ __launch_bounds__(256, 3) void k_gemm(const __bf16* __restrict__ xbf,
                                              const __bf16* __restrict__ Mbf,
                                              const __bf16* __restrict__ W1bf,
                                              const float* __restrict__ dvec,
                                              __bf16* __restrict__ c,
                                              float* __restrict__ proj_a,
                                              float* __restrict__ proj_b){
    int lane = threadIdx.x & 63, wv = threadIdx.x >> 6;
    int wm = wv & 1, wn = wv >> 1;
    int nb = blockIdx.x * 64 + wm * 32;    // 32 nodes per wave
    int ob = wn * 128;                     // output half per wave
    int l15 = lane & 15, quad = lane >> 4;
    f32x4 acc[2][8], accp[2];
    #pragma unroll
    for (int mi = 0; mi < 2; ++mi){
        accp[mi] = f32x4{0.f, 0.f, 0.f, 0.f};
        #pragma unroll
        for (int ni = 0; ni < 8; ++ni) acc[mi][ni] = f32x4{0.f, 0.f, 0.f, 0.f};
    }
    const __bf16* xg[2];
    #pragma unroll
    for (int mi = 0; mi < 2; ++mi){
        int row = nb + mi * 16 + l15;
        if (row >= N_NODES) row = N_NODES - 1;   // clamp for tail
        xg[mi] = xbf + (size_t)row * 256 + quad * 8;
    }
    for (int k0 = 0; k0 < 256; k0 += 32){
        bf16x8 a[2];
        #pragma unroll
        for (int mi = 0; mi < 2; ++mi) a[mi] = *(const bf16x8*)(xg[mi] + k0);
        #pragma unroll
        for (int ni = 0; ni < 8; ++ni){
            bf16x8 b = *(const bf16x8*)(Mbf + (size_t)(ob + ni * 16 + l15) * 256 + k0 + quad * 8);
            acc[0][ni] = __builtin_amdgcn_mfma_f32_16x16x32_bf16(a[0], b, acc[0][ni], 0, 0, 0);
            acc[1][ni] = __builtin_amdgcn_mfma_f32_16x16x32_bf16(a[1], b, acc[1][ni], 0, 0, 0);
        }
        if (wn == 0){
            bf16x8 bw = *(const bf16x8*)(W1bf + (size_t)l15 * 256 + k0 + quad * 8);
            accp[0] = __builtin_amdgcn_mfma_f32_16x16x32_bf16(a[0], bw, accp[0], 0, 0, 0);
            accp[1] = __builtin_amdgcn_mfma_f32_16x16x32_bf16(a[1], bw, accp[1], 0, 0, 0);
        }
    }
    #pragma unroll
    for (int ni = 0; ni < 8; ++ni){
        int o = ob + ni * 16 + l15;
        float dv = dvec[o];
        #pragma unroll
        for (int mi = 0; mi < 2; ++mi){
            int nrow = nb + mi * 16 + quad * 4;
            #pragma unroll
            for (int r = 0; r < 4; ++r){
                int node = nrow + r;
                if (node < N_NODES) c[(size_t)node * 256 + o] = (__bf16)(acc[mi][ni][r] + dv);
            }
        }
    }
    if (wn == 0 && l15 < 8){
        #pragma unroll
        for (int mi = 0; mi < 2; ++mi){
            int nrow = nb + mi * 16 + quad * 4;
            #pragma unroll
            for (int r = 0; r < 4; ++r){
                int node = nrow + r;
                if (node < N_NODES){
                    float v = accp[mi][r];
                    if (l15 < 4) proj_a[node * 4 + l15] = v;
                    else         proj_b[node * 4 + (l15 - 4)] = v;
                }
            }
        }
    }
}

// ---- K_edge: local dtype detect + softmax gate + bucket scatter {col, w*4 bf16}
__global__ __launch_bounds__(256) void k_edge(const void* __restrict__ row_raw,
                                              const void* __restrict__ col_raw,
                                              const float* __restrict__ proj_a,
                                              const float* __restrict__ proj_b,
                                              const float* __restrict__ asg_b1,
                                              const float* __restrict__ asg_W2,
                                              const float* __restrict__ asg_b2,
                                              int* __restrict__ deg,
                                              int4* __restrict__ bucket){
    __shared__ int s_is64;
    int t = threadIdx.x;
    if (t == 0) s_is64 = 1;
    __syncthreads();
    // sample the first 512 words of both arrays: int64 inputs have all odd words 0
    unsigned v = ((const unsigned*)row_raw)[2 * t + 1] | ((const unsigned*)col_raw)[2 * t + 1];
    if (v) s_is64 = 0;
    __syncthreads();

    int e = blockIdx.x * 256 + t;
    if (e >= N_EDGES) return;
    int r, cl;
    if (s_is64){
        r  = (int)((const long long*)row_raw)[e];
        cl = (int)((const long long*)col_raw)[e];
    } else {
        r  = ((const int*)row_raw)[e];
        cl = ((const int*)col_raw)[e];
    }
    float4 pa = *(const float4*)(proj_a + (size_t)cl * 4);
    float4 pb = *(const float4*)(proj_b + (size_t)r * 4);
    float h1[4];
    h1[0] = pa.x + pb.x + asg_b1[0];
    h1[1] = pa.y + pb.y + asg_b1[1];
    h1[2] = pa.z + pb.z + asg_b1[2];
    h1[3] = pa.w + pb.w + asg_b1[3];
    float h2[4];
    #pragma unroll
    for (int i = 0; i < 4; ++i){
        float s = asg_b2[i];
        #pragma unroll
        for (int j = 0; j < 4; ++j) s += asg_W2[i * 4 + j] * h1[j];
        h2[i] = s;
    }
    float m = fmaxf(fmaxf(h2[0], h2[1]), fmaxf(h2[2], h2[3]));
    float e0 = __expf(h2[0] - m), e1 = __expf(h2[1] - m);
    float e2 = __expf(h2[2] - m), e3 = __expf(h2[3] - m);
    float inv = 1.f / (e0 + e1 + e2 + e3);
    unsigned b0 = f2bf(e0 * inv), b1 = f2bf(e1 * inv);
    unsigned b2 = f2bf(e2 * inv), b3 = f2bf(e3 * inv);
    int4 rec;
    rec.x = cl;
    rec.y = (int)(b0 | (b1 << 16));
    rec.z = (int)(b2 | (b3 << 16));
    rec.w = 0;
    int pos = atomicAdd(&deg[r], 1);
    if (pos < BCAP) bucket[(size_t)r * BCAP + pos] = rec;
}

// ---- K_node v2: ONE WAVE PER NODE. Zero barriers, zero LDS.
__global__ __launch_bounds__(256) void k_node(const __bf16* __restrict__ c,
                                              const int* __restrict__ deg,
                                              const int4* __restrict__ bucket,
                                              const float* __restrict__ bias,
                                              const float* __restrict__ cls_W,
                                              const float* __restrict__ cls_b,
                                              float* __restrict__ out_h,
                                              float* __restrict__ out_logits){
    int wv = __builtin_amdgcn_readfirstlane((int)(threadIdx.x >> 6));
    int l  = threadIdx.x & 63;
    int n  = blockIdx.x * 4 + wv;
    int k2 = l >> 4;

    // per-lane constants (L1/L2-resident)
    float4 bi = *(const float4*)(bias  + l * 4);
    float4 w0 = *(const float4*)(cls_W + 0 * 256 + l * 4);
    float4 w1 = *(const float4*)(cls_W + 1 * 256 + l * 4);
    float4 w2 = *(const float4*)(cls_W + 2 * 256 + l * 4);
    float4 w3 = *(const float4*)(cls_W + 3 * 256 + l * 4);

    int dn = deg[n]; if (dn > BCAP) dn = BCAP;
    const int4* rec = bucket + (size_t)n * BCAP;
    const __bf16* cb = c + (size_t)l * 4;

    bool hi2 = (k2 & 2) != 0;    // use rec.z (k=2,3) vs rec.y (k=0,1)
    bool odd = (k2 & 1) != 0;    // use hi16 vs lo16

    float a0 = 0.f, a1 = 0.f, a2 = 0.f, a3 = 0.f;
    #pragma unroll 4
    for (int i = 0; i < dn; ++i){
        int4 rc = rec[i];                         // wave-uniform -> s_load
        int  ww = hi2 ? rc.z : rc.y;
        unsigned wb = odd ? ((unsigned)ww & 0xffff0000u) : ((unsigned)ww << 16);
        float w = bits2f(wb);
        uint2 vv = *(const uint2*)(cb + (size_t)rc.x * 256);   // 8B/lane, 512B/wave
        a0 += w * bits2f(vv.x << 16);
        a1 += w * bits2f(vv.x & 0xffff0000u);
        a2 += w * bits2f(vv.y << 16);
        a3 += w * bits2f(vv.y & 0xffff0000u);
    }
    a0 += bi.x; a1 += bi.y; a2 += bi.z; a3 += bi.w;

    // norm over each 64-feature group = 16 consecutive lanes
    float ss = a0 * a0 + a1 * a1 + a2 * a2 + a3 * a3;
    ss += __shfl_xor(ss, 1);
    ss += __shfl_xor(ss, 2);
    ss += __shfl_xor(ss, 4);
    ss += __shfl_xor(ss, 8);
    float nrm = fmaxf(sqrtf(ss), EPS);
    float h0 = a0 / nrm, h1 = a1 / nrm, h2 = a2 / nrm, h3 = a3 / nrm;
    *(float4*)(out_h + (size_t)n * 256 + l * 4) = make_float4(h0, h1, h2, h3);

    // logits: per-lane partial dot then full-wave butterfly
    float p0 = h0 * w0.x + h1 * w0.y + h2 * w0.z + h3 * w0.w;
    float p1 = h0 * w1.x + h1 * w1.y + h2 * w1.z + h3 * w1.w;
    float p2 = h0 * w2.x + h1 * w2.y + h2 * w2.z + h3 * w2.w;
    float p3 = h0 * w3.x + h1 * w3.y + h2 * w3.z + h3 * w3.w;
    #pragma unroll
    for (int off = 1; off < 64; off <<= 1){
        p0 += __shfl_xor(p0, off);
        p1 += __shfl_xor(p1, off);
        p2 += __shfl_xor(p2, off);
        p3 += __shfl_xor(p3, off);
    }
    if (l == 0){
        float4 lg = make_float4(p0 + cls_b[0], p1 + cls_b[1],
                                p2 + cls_b[2], p3 + cls_b[3]);
        *(float4*)(out_logits + (size_t)n * 4) = lg;
    }
}

extern "C" void kernel_launch(void* const* d_in, const int* in_sizes, int n_in,
                              void* d_out, int out_size, void* d_ws, size_t ws_size,
                              hipStream_t stream){
    const float* x       = (const float*)d_in[0];
    const void*  row_raw = d_in[1];
    const void*  col_raw = d_in[2];
    const float* asg_W1  = (const float*)d_in[3];
    const float* asg_b1  = (const float*)d_in[4];
    const float* asg_W2  = (const float*)d_in[5];
    const float* asg_b2  = (const float*)d_in[6];
    const float* lin_W   = (const float*)d_in[7];
    const float* lin_b   = (const float*)d_in[8];
    const float* conv_W  = (const float*)d_in[9];
    const float* bias    = (const float*)d_in[10];
    const float* cls_W   = (const float*)d_in[11];
    const float* cls_b   = (const float*)d_in[12];

    char* ws = (char*)d_ws;
    size_t off = 0;
    auto alloc = [&](size_t bytes) -> void* {
        void* p = ws + off;
        off += (bytes + 255) & ~(size_t)255;
        return p;
    };
    __bf16* c      = (__bf16*)alloc((size_t)N_NODES * 256 * 2);       // 51.2 MB
    int4*   bucket = (int4*)alloc((size_t)N_NODES * BCAP * 16);       // 102.4 MB
    float*  proj_a = (float*)alloc((size_t)N_NODES * 4 * 4);
    float*  proj_b = (float*)alloc((size_t)N_NODES * 4 * 4);
    __bf16* Mbf    = (__bf16*)alloc(65536 * 2);
    __bf16* W1bf   = (__bf16*)alloc(4096 * 2);
    float*  dvec   = (float*)alloc(256 * 4);
    int*    deg    = (int*)alloc((size_t)N_NODES * 4);

    // xbf (51.2 MB) aliases the bucket region: written by k_init, consumed by
    // k_gemm, then dead before k_edge rebuilds bucket (stream-ordered).
    __bf16* xbf = (__bf16*)bucket;

    float* out_h = (float*)d_out;
    float* out_l = out_h + (size_t)N_NODES * 256;

    hipLaunchKernelGGL(k_init, dim3(13163), dim3(256), 0, stream,
                       deg, lin_W, lin_b, conv_W, Mbf, dvec, asg_W1, W1bf, x, xbf);
    hipLaunchKernelGGL(k_gemm, dim3((N_NODES + 63) / 64), dim3(256), 0, stream,
                       (const __bf16*)xbf, (const __bf16*)Mbf, (const __bf16*)W1bf,
                       dvec, c, proj_a, proj_b);
    hipLaunchKernelGGL(k_edge, dim3(N_EDGES / 256), dim3(256), 0, stream,
                       row_raw, col_raw, proj_a, proj_b, asg_b1, asg_W2, asg_b2,
                       deg, bucket);
    hipLaunchKernelGGL(k_node, dim3(N_NODES / 4), dim3(256), 0, stream,
                       c, deg, bucket, bias, cls_W, cls_b, out_h, out_l);
}

// Round 9
// 500.332 us; speedup vs baseline: 1.0307x; 1.0119x over previous
//
#include <hip/hip_runtime.h>
#include <hip/hip_bf16.h>

#define N_NODES 100000
#define N_EDGES 1600000
#define BCAP    64          // bucket capacity per node (max degree; Poisson(16) tail ~1e-20)
#define EPS     1e-12f

typedef __bf16 bf16x8 __attribute__((ext_vector_type(8)));
typedef float  f32x4  __attribute__((ext_vector_type(4)));

__device__ __forceinline__ unsigned short f2bf(float f){
    union { float f; unsigned int i; } v; v.f = f;
    unsigned int x = v.i;
    return (unsigned short)((x + 0x7fffu + ((x >> 16) & 1u)) >> 16);
}
__device__ __forceinline__ float bits2f(unsigned int u){
    union { unsigned int i; float f; } v; v.i = u; return v.f;
}

// ---- K_init: blocks [0,390] zero deg; [391,646] fuse M/dvec; [647,662] W1 tile
__global__ void k_init(int* __restrict__ deg,
                       const float* __restrict__ lin_W,
                       const float* __restrict__ lin_b,
                       const float* __restrict__ conv_W,
                       __bf16* __restrict__ Mbf,
                       float* __restrict__ dvec,
                       const float* __restrict__ asg_W1,
                       __bf16* __restrict__ W1bf){
    int b = blockIdx.x;
    int t = threadIdx.x;
    if (b < 391){
        int i = b * 256 + t;
        if (i < N_NODES) deg[i] = 0;
    } else if (b < 647){
        int id = (b - 391) * 256 + t;             // 0..65535
        int f  = id & 255;
        int o  = id >> 8;                          // k*64+q
        int k  = o >> 6;
        const float* cw = conv_W + o * 64;         // conv_W[k][q][p]
        const float* lw = lin_W + k * 64 * 256 + f;// lin_W[k][p][f]
        float s = 0.f;
        #pragma unroll 8
        for (int p = 0; p < 64; ++p) s += cw[p] * lw[p * 256];
        Mbf[id] = (__bf16)s;
        if (f == 0){
            const float* lb = lin_b + k * 64;
            float d = 0.f;
            for (int p = 0; p < 64; ++p) d += lb[p] * cw[p];
            dvec[o] = d;
        }
    } else {
        int id = (b - 647) * 256 + t;              // 0..4095
        int f  = id & 255;
        int o  = id >> 8;                          // 0..15
        float v = 0.f;
        if (o < 4)      v = asg_W1[o * 512 + f];
        else if (o < 8) v = asg_W1[(o - 4) * 512 + 256 + f];
        W1bf[id] = (__bf16)v;
    }
}

// ---- K_proj: proj_a/b only (100Kx8 GEMV via MFMA). Wave = 32 nodes. 782 blocks.
__global__ __launch_bounds__(256, 4) void k_proj(const float* __restrict__ x,
                                                 const __bf16* __restrict__ W1bf,
                                                 float* __restrict__ proj_a,
                                                 float* __restrict__ proj_b){
    int lane = threadIdx.x & 63, wv = threadIdx.x >> 6;
    int nb = blockIdx.x * 128 + wv * 32;
    int l15 = lane & 15, quad = lane >> 4;
    f32x4 accp[2];
    accp[0] = f32x4{0.f, 0.f, 0.f, 0.f};
    accp[1] = f32x4{0.f, 0.f, 0.f, 0.f};
    const float* xg[2];
    #pragma unroll
    for (int mi = 0; mi < 2; ++mi){
        int row = nb + mi * 16 + l15;
        if (row >= N_NODES) row = N_NODES - 1;
        xg[mi] = x + (size_t)row * 256 + quad * 8;
    }
    for (int k0 = 0; k0 < 256; k0 += 32){
        bf16x8 a[2];
        #pragma unroll
        for (int mi = 0; mi < 2; ++mi){
            float4 lo = *(const float4*)(xg[mi] + k0);
            float4 hi = *(const float4*)(xg[mi] + k0 + 4);
            a[mi][0] = (__bf16)lo.x; a[mi][1] = (__bf16)lo.y;
            a[mi][2] = (__bf16)lo.z; a[mi][3] = (__bf16)lo.w;
            a[mi][4] = (__bf16)hi.x; a[mi][5] = (__bf16)hi.y;
            a[mi][6] = (__bf16)hi.z; a[mi][7] = (__bf16)hi.w;
        }
        bf16x8 bw = *(const bf16x8*)(W1bf + (size_t)l15 * 256 + k0 + quad * 8);
        accp[0] = __builtin_amdgcn_mfma_f32_16x16x32_bf16(a[0], bw, accp[0], 0, 0, 0);
        accp[1] = __builtin_amdgcn_mfma_f32_16x16x32_bf16(a[1], bw, accp[1], 0, 0, 0);
    }
    if (l15 < 8){
        #pragma unroll
        for (int mi = 0; mi < 2; ++mi){
            int nrow = nb + mi * 16 + quad * 4;
            #pragma unroll
            for (int r = 0; r < 4; ++r){
                int node = nrow + r;
                if (node < N_NODES){
                    float v = accp[mi][r];
                    if (l15 < 4) proj_a[node * 4 + l15] = v;
                    else         proj_b[node * 4 + (l15 - 4)] = v;
                }
            }
        }
    }
}

// ---- K_ge: FUSED heterogeneous kernel. b%5==0 -> c-GEMM block (1563 of them);
// else -> edge block (6250). Interleaved so every CU co-hosts both types:
// GEMM is MFMA/latency-bound, edge is scatter/write-bound -> pipes overlap.
__global__ __launch_bounds__(256, 3) void k_ge(const float* __restrict__ x,
                                               const __bf16* __restrict__ Mbf,
                                               const float* __restrict__ dvec,
                                               __bf16* __restrict__ c,
                                               const void* __restrict__ row_raw,
                                               const void* __restrict__ col_raw,
                                               const float* __restrict__ proj_a,
                                               const float* __restrict__ proj_b,
                                               const float* __restrict__ asg_b1,
                                               const float* __restrict__ asg_W2,
                                               const float* __restrict__ asg_b2,
                                               int* __restrict__ deg,
                                               int4* __restrict__ bucket){
    __shared__ int s_is64;
    int b = blockIdx.x;
    int t = threadIdx.x;
    if (b % 5 == 0){
        // ----- GEMM path: 64 nodes/block, 2Mx2N waves, wave = 32n x 128o -----
        int gid = b / 5;
        int lane = t & 63, wv = t >> 6;
        int wm = wv & 1, wn = wv >> 1;
        int nb = gid * 64 + wm * 32;
        int ob = wn * 128;
        int l15 = lane & 15, quad = lane >> 4;
        f32x4 acc[2][8];
        #pragma unroll
        for (int mi = 0; mi < 2; ++mi)
            #pragma unroll
            for (int ni = 0; ni < 8; ++ni) acc[mi][ni] = f32x4{0.f, 0.f, 0.f, 0.f};
        const float* xg[2];
        #pragma unroll
        for (int mi = 0; mi < 2; ++mi){
            int row = nb + mi * 16 + l15;
            if (row >= N_NODES) row = N_NODES - 1;
            xg[mi] = x + (size_t)row * 256 + quad * 8;
        }
        for (int k0 = 0; k0 < 256; k0 += 32){
            bf16x8 a[2];
            #pragma unroll
            for (int mi = 0; mi < 2; ++mi){
                float4 lo = *(const float4*)(xg[mi] + k0);
                float4 hi = *(const float4*)(xg[mi] + k0 + 4);
                a[mi][0] = (__bf16)lo.x; a[mi][1] = (__bf16)lo.y;
                a[mi][2] = (__bf16)lo.z; a[mi][3] = (__bf16)lo.w;
                a[mi][4] = (__bf16)hi.x; a[mi][5] = (__bf16)hi.y;
                a[mi][6] = (__bf16)hi.z; a[mi][7] = (__bf16)hi.w;
            }
            #pragma unroll
            for (int ni = 0; ni < 8; ++ni){
                bf16x8 bb = *(const bf16x8*)(Mbf + (size_t)(ob + ni * 16 + l15) * 256 + k0 + quad * 8);
                acc[0][ni] = __builtin_amdgcn_mfma_f32_16x16x32_bf16(a[0], bb, acc[0][ni], 0, 0, 0);
                acc[1][ni] = __builtin_amdgcn_mfma_f32_16x16x32_bf16(a[1], bb, acc[1][ni], 0, 0, 0);
            }
        }
        #pragma unroll
        for (int ni = 0; ni < 8; ++ni){
            int o = ob + ni * 16 + l15;
            float dv = dvec[o];
            #pragma unroll
            for (int mi = 0; mi < 2; ++mi){
                int nrow = nb + mi * 16 + quad * 4;
                #pragma unroll
                for (int r = 0; r < 4; ++r){
                    int node = nrow + r;
                    if (node < N_NODES) c[(size_t)node * 256 + o] = (__bf16)(acc[mi][ni][r] + dv);
                }
            }
        }
    } else {
        // ----- EDGE path -----
        int eid = b - b / 5 - 1;
        if (t == 0) s_is64 = 1;
        __syncthreads();
        unsigned v = ((const unsigned*)row_raw)[2 * t + 1] | ((const unsigned*)col_raw)[2 * t + 1];
        if (v) s_is64 = 0;
        __syncthreads();

        int e = eid * 256 + t;
        if (e >= N_EDGES) return;
        int r, cl;
        if (s_is64){
            r  = (int)((const long long*)row_raw)[e];
            cl = (int)((const long long*)col_raw)[e];
        } else {
            r  = ((const int*)row_raw)[e];
            cl = ((const int*)col_raw)[e];
        }
        float4 pa = *(const float4*)(proj_a + (size_t)cl * 4);
        float4 pb = *(const float4*)(proj_b + (size_t)r * 4);
        float h1[4];
        h1[0] = pa.x + pb.x + asg_b1[0];
        h1[1] = pa.y + pb.y + asg_b1[1];
        h1[2] = pa.z + pb.z + asg_b1[2];
        h1[3] = pa.w + pb.w + asg_b1[3];
        float h2[4];
        #pragma unroll
        for (int i = 0; i < 4; ++i){
            float s = asg_b2[i];
            #pragma unroll
            for (int j = 0; j < 4; ++j) s += asg_W2[i * 4 + j] * h1[j];
            h2[i] = s;
        }
        float m = fmaxf(fmaxf(h2[0], h2[1]), fmaxf(h2[2], h2[3]));
        float e0 = __expf(h2[0] - m), e1 = __expf(h2[1] - m);
        float e2 = __expf(h2[2] - m), e3 = __expf(h2[3] - m);
        float inv = 1.f / (e0 + e1 + e2 + e3);
        unsigned b0 = f2bf(e0 * inv), b1 = f2bf(e1 * inv);
        unsigned b2 = f2bf(e2 * inv), b3 = f2bf(e3 * inv);
        int4 rec;
        rec.x = cl;
        rec.y = (int)(b0 | (b1 << 16));
        rec.z = (int)(b2 | (b3 << 16));
        rec.w = 0;
        int pos = atomicAdd(&deg[r], 1);
        if (pos < BCAP) bucket[(size_t)r * BCAP + pos] = rec;
    }
}

// ---- K_node v2: ONE WAVE PER NODE. Zero barriers, zero LDS.
__global__ __launch_bounds__(256) void k_node(const __bf16* __restrict__ c,
                                              const int* __restrict__ deg,
                                              const int4* __restrict__ bucket,
                                              const float* __restrict__ bias,
                                              const float* __restrict__ cls_W,
                                              const float* __restrict__ cls_b,
                                              float* __restrict__ out_h,
                                              float* __restrict__ out_logits){
    int wv = __builtin_amdgcn_readfirstlane((int)(threadIdx.x >> 6));
    int l  = threadIdx.x & 63;
    int n  = blockIdx.x * 4 + wv;
    int k2 = l >> 4;

    // per-lane constants (L1/L2-resident)
    float4 bi = *(const float4*)(bias  + l * 4);
    float4 w0 = *(const float4*)(cls_W + 0 * 256 + l * 4);
    float4 w1 = *(const float4*)(cls_W + 1 * 256 + l * 4);
    float4 w2 = *(const float4*)(cls_W + 2 * 256 + l * 4);
    float4 w3 = *(const float4*)(cls_W + 3 * 256 + l * 4);

    int dn = deg[n]; if (dn > BCAP) dn = BCAP;
    const int4* rec = bucket + (size_t)n * BCAP;
    const __bf16* cb = c + (size_t)l * 4;

    bool hi2 = (k2 & 2) != 0;    // use rec.z (k=2,3) vs rec.y (k=0,1)
    bool odd = (k2 & 1) != 0;    // use hi16 vs lo16

    float a0 = 0.f, a1 = 0.f, a2 = 0.f, a3 = 0.f;
    #pragma unroll 4
    for (int i = 0; i < dn; ++i){
        int4 rc = rec[i];                         // wave-uniform -> s_load
        int  ww = hi2 ? rc.z : rc.y;
        unsigned wb = odd ? ((unsigned)ww & 0xffff0000u) : ((unsigned)ww << 16);
        float w = bits2f(wb);
        uint2 vv = *(const uint2*)(cb + (size_t)rc.x * 256);   // 8B/lane, 512B/wave
        a0 += w * bits2f(vv.x << 16);
        a1 += w * bits2f(vv.x & 0xffff0000u);
        a2 += w * bits2f(vv.y << 16);
        a3 += w * bits2f(vv.y & 0xffff0000u);
    }
    a0 += bi.x; a1 += bi.y; a2 += bi.z; a3 += bi.w;

    // norm over each 64-feature group = 16 consecutive lanes
    float ss = a0 * a0 + a1 * a1 + a2 * a2 + a3 * a3;
    ss += __shfl_xor(ss, 1);
    ss += __shfl_xor(ss, 2);
    ss += __shfl_xor(ss, 4);
    ss += __shfl_xor(ss, 8);
    float nrm = fmaxf(sqrtf(ss), EPS);
    float h0 = a0 / nrm, h1 = a1 / nrm, h2 = a2 / nrm, h3 = a3 / nrm;
    *(float4*)(out_h + (size_t)n * 256 + l * 4) = make_float4(h0, h1, h2, h3);

    // logits: per-lane partial dot then full-wave butterfly
    float p0 = h0 * w0.x + h1 * w0.y + h2 * w0.z + h3 * w0.w;
    float p1 = h0 * w1.x + h1 * w1.y + h2 * w1.z + h3 * w1.w;
    float p2 = h0 * w2.x + h1 * w2.y + h2 * w2.z + h3 * w2.w;
    float p3 = h0 * w3.x + h1 * w3.y + h2 * w3.z + h3 * w3.w;
    #pragma unroll
    for (int off = 1; off < 64; off <<= 1){
        p0 += __shfl_xor(p0, off);
        p1 += __shfl_xor(p1, off);
        p2 += __shfl_xor(p2, off);
        p3 += __shfl_xor(p3, off);
    }
    if (l == 0){
        float4 lg = make_float4(p0 + cls_b[0], p1 + cls_b[1],
                                p2 + cls_b[2], p3 + cls_b[3]);
        *(float4*)(out_logits + (size_t)n * 4) = lg;
    }
}

extern "C" void kernel_launch(void* const* d_in, const int* in_sizes, int n_in,
                              void* d_out, int out_size, void* d_ws, size_t ws_size,
                              hipStream_t stream){
    const float* x       = (const float*)d_in[0];
    const void*  row_raw = d_in[1];
    const void*  col_raw = d_in[2];
    const float* asg_W1  = (const float*)d_in[3];
    const float* asg_b1  = (const float*)d_in[4];
    const float* asg_W2  = (const float*)d_in[5];
    const float* asg_b2  = (const float*)d_in[6];
    const float* lin_W   = (const float*)d_in[7];
    const float* lin_b   = (const float*)d_in[8];
    const float* conv_W  = (const float*)d_in[9];
    const float* bias    = (const float*)d_in[10];
    const float* cls_W   = (const float*)d_in[11];
    const float* cls_b   = (const float*)d_in[12];

    char* ws = (char*)d_ws;
    size_t off = 0;
    auto alloc = [&](size_t bytes) -> void* {
        void* p = ws + off;
        off += (bytes + 255) & ~(size_t)255;
        return p;
    };
    __bf16* c      = (__bf16*)alloc((size_t)N_NODES * 256 * 2);       // 51.2 MB
    int4*   bucket = (int4*)alloc((size_t)N_NODES * BCAP * 16);       // 102.4 MB
    float*  proj_a = (float*)alloc((size_t)N_NODES * 4 * 4);
    float*  proj_b = (float*)alloc((size_t)N_NODES * 4 * 4);
    __bf16* Mbf    = (__bf16*)alloc(65536 * 2);
    __bf16* W1bf   = (__bf16*)alloc(4096 * 2);
    float*  dvec   = (float*)alloc(256 * 4);
    int*    deg    = (int*)alloc((size_t)N_NODES * 4);

    float* out_h = (float*)d_out;
    float* out_l = out_h + (size_t)N_NODES * 256;

    hipLaunchKernelGGL(k_init, dim3(663), dim3(256), 0, stream,
                       deg, lin_W, lin_b, conv_W, Mbf, dvec, asg_W1, W1bf);
    hipLaunchKernelGGL(k_proj, dim3((N_NODES + 127) / 128), dim3(256), 0, stream,
                       x, (const __bf16*)W1bf, proj_a, proj_b);
    hipLaunchKernelGGL(k_ge, dim3(7813), dim3(256), 0, stream,
                       x, (const __bf16*)Mbf, dvec, c,
                       row_raw, col_raw, proj_a, proj_b, asg_b1, asg_W2, asg_b2,
                       deg, bucket);
    hipLaunchKernelGGL(k_node, dim3(N_NODES / 4), dim3(256), 0, stream,
                       c, deg, bucket, bias, cls_W, cls_b, out_h, out_l);
}

// Round 11
// 496.823 us; speedup vs baseline: 1.0380x; 1.0071x over previous
//
#include <hip/hip_runtime.h>
#include <hip/hip_bf16.h>

#define N_NODES 100000
#define N_EDGES 1600000
#define BCAP    64          // bucket capacity per node (max degree; Poisson(16) tail ~1e-20)
#define EPS     1e-12f

typedef __bf16 bf16x8 __attribute__((ext_vector_type(8)));
typedef float  f32x4  __attribute__((ext_vector_type(4)));

__device__ __forceinline__ unsigned short f2bf(float f){
    union { float f; unsigned int i; } v; v.f = f;
    unsigned int x = v.i;
    return (unsigned short)((x + 0x7fffu + ((x >> 16) & 1u)) >> 16);
}
__device__ __forceinline__ float bits2f(unsigned int u){
    union { unsigned int i; float f; } v; v.i = u; return v.f;
}

// ---- K_init: [0,390] zero deg; [391,646] fuse M/dvec; [647,1428] proj_a/b
// (proj blocks read asg_W1 directly -> no dependency on other init blocks)
__global__ void k_init(int* __restrict__ deg,
                       const float* __restrict__ lin_W,
                       const float* __restrict__ lin_b,
                       const float* __restrict__ conv_W,
                       __bf16* __restrict__ Mbf,
                       float* __restrict__ dvec,
                       const float* __restrict__ asg_W1,
                       const float* __restrict__ x,
                       float* __restrict__ proj_a,
                       float* __restrict__ proj_b){
    int b = blockIdx.x;
    int t = threadIdx.x;
    if (b < 391){
        int i = b * 256 + t;
        if (i < N_NODES) deg[i] = 0;
    } else if (b < 647){
        int id = (b - 391) * 256 + t;             // 0..65535
        int f  = id & 255;
        int o  = id >> 8;                          // k*64+q
        int k  = o >> 6;
        const float* cw = conv_W + o * 64;         // conv_W[k][q][p]
        const float* lw = lin_W + k * 64 * 256 + f;// lin_W[k][p][f]
        float s = 0.f;
        #pragma unroll 8
        for (int p = 0; p < 64; ++p) s += cw[p] * lw[p * 256];
        Mbf[id] = (__bf16)s;
        if (f == 0){
            const float* lb = lin_b + k * 64;
            float d = 0.f;
            for (int p = 0; p < 64; ++p) d += lb[p] * cw[p];
            dvec[o] = d;
        }
    } else {
        // ---- proj path: block = 128 nodes, 4 waves x 32 nodes, MFMA GEMV ----
        int p = b - 647;
        int lane = t & 63, wv = t >> 6;
        int nb = p * 128 + wv * 32;
        int l15 = lane & 15, quad = lane >> 4;
        f32x4 accp[2];
        accp[0] = f32x4{0.f, 0.f, 0.f, 0.f};
        accp[1] = f32x4{0.f, 0.f, 0.f, 0.f};
        const float* xg[2];
        #pragma unroll
        for (int mi = 0; mi < 2; ++mi){
            int row = nb + mi * 16 + l15;
            if (row >= N_NODES) row = N_NODES - 1;
            xg[mi] = x + (size_t)row * 256 + quad * 8;
        }
        // W1 row for this lane, straight from asg_W1 (rows 8..15 are zero)
        const float* wrow = asg_W1;                // dummy base for l15>=8
        if (l15 < 4)      wrow = asg_W1 + l15 * 512;
        else if (l15 < 8) wrow = asg_W1 + (l15 - 4) * 512 + 256;
        bool wz = (l15 >= 8);
        for (int k0 = 0; k0 < 256; k0 += 32){
            bf16x8 a[2];
            #pragma unroll
            for (int mi = 0; mi < 2; ++mi){
                float4 lo = *(const float4*)(xg[mi] + k0);
                float4 hi = *(const float4*)(xg[mi] + k0 + 4);
                a[mi][0] = (__bf16)lo.x; a[mi][1] = (__bf16)lo.y;
                a[mi][2] = (__bf16)lo.z; a[mi][3] = (__bf16)lo.w;
                a[mi][4] = (__bf16)hi.x; a[mi][5] = (__bf16)hi.y;
                a[mi][6] = (__bf16)hi.z; a[mi][7] = (__bf16)hi.w;
            }
            bf16x8 bw;
            if (!wz){
                float4 lo = *(const float4*)(wrow + k0 + quad * 8);
                float4 hi = *(const float4*)(wrow + k0 + quad * 8 + 4);
                bw[0] = (__bf16)lo.x; bw[1] = (__bf16)lo.y;
                bw[2] = (__bf16)lo.z; bw[3] = (__bf16)lo.w;
                bw[4] = (__bf16)hi.x; bw[5] = (__bf16)hi.y;
                bw[6] = (__bf16)hi.z; bw[7] = (__bf16)hi.w;
            } else {
                bw[0] = (__bf16)0.f; bw[1] = (__bf16)0.f; bw[2] = (__bf16)0.f; bw[3] = (__bf16)0.f;
                bw[4] = (__bf16)0.f; bw[5] = (__bf16)0.f; bw[6] = (__bf16)0.f; bw[7] = (__bf16)0.f;
            }
            accp[0] = __builtin_amdgcn_mfma_f32_16x16x32_bf16(a[0], bw, accp[0], 0, 0, 0);
            accp[1] = __builtin_amdgcn_mfma_f32_16x16x32_bf16(a[1], bw, accp[1], 0, 0, 0);
        }
        if (l15 < 8){
            #pragma unroll
            for (int mi = 0; mi < 2; ++mi){
                int nrow = nb + mi * 16 + quad * 4;
                #pragma unroll
                for (int r = 0; r < 4; ++r){
                    int node = nrow + r;
                    if (node < N_NODES){
                        float v = accp[mi][r];
                        if (l15 < 4) proj_a[node * 4 + l15] = v;
                        else         proj_b[node * 4 + (l15 - 4)] = v;
                    }
                }
            }
        }
    }
}

// ---- K_ge: FUSED heterogeneous kernel. b%5==0 -> c-GEMM block (1563 of them);
// else -> edge block (6250). launch_bounds(256,4): 116 regs/lane fits 4 waves/SIMD.
__global__ __launch_bounds__(256, 4) void k_ge(const float* __restrict__ x,
                                               const __bf16* __restrict__ Mbf,
                                               const float* __restrict__ dvec,
                                               __bf16* __restrict__ c,
                                               const void* __restrict__ row_raw,
                                               const void* __restrict__ col_raw,
                                               const float* __restrict__ proj_a,
                                               const float* __restrict__ proj_b,
                                               const float* __restrict__ asg_b1,
                                               const float* __restrict__ asg_W2,
                                               const float* __restrict__ asg_b2,
                                               int* __restrict__ deg,
                                               int4* __restrict__ bucket){
    __shared__ int s_is64;
    int b = blockIdx.x;
    int t = threadIdx.x;
    if (b % 5 == 0){
        // ----- GEMM path: 64 nodes/block, 2Mx2N waves, wave = 32n x 128o -----
        int gid = b / 5;
        int lane = t & 63, wv = t >> 6;
        int wm = wv & 1, wn = wv >> 1;
        int nb = gid * 64 + wm * 32;
        int ob = wn * 128;
        int l15 = lane & 15, quad = lane >> 4;
        f32x4 acc[2][8];
        #pragma unroll
        for (int mi = 0; mi < 2; ++mi)
            #pragma unroll
            for (int ni = 0; ni < 8; ++ni) acc[mi][ni] = f32x4{0.f, 0.f, 0.f, 0.f};
        const float* xg[2];
        #pragma unroll
        for (int mi = 0; mi < 2; ++mi){
            int row = nb + mi * 16 + l15;
            if (row >= N_NODES) row = N_NODES - 1;
            xg[mi] = x + (size_t)row * 256 + quad * 8;
        }
        for (int k0 = 0; k0 < 256; k0 += 32){
            bf16x8 a[2];
            #pragma unroll
            for (int mi = 0; mi < 2; ++mi){
                float4 lo = *(const float4*)(xg[mi] + k0);
                float4 hi = *(const float4*)(xg[mi] + k0 + 4);
                a[mi][0] = (__bf16)lo.x; a[mi][1] = (__bf16)lo.y;
                a[mi][2] = (__bf16)lo.z; a[mi][3] = (__bf16)lo.w;
                a[mi][4] = (__bf16)hi.x; a[mi][5] = (__bf16)hi.y;
                a[mi][6] = (__bf16)hi.z; a[mi][7] = (__bf16)hi.w;
            }
            #pragma unroll
            for (int ni = 0; ni < 8; ++ni){
                bf16x8 bb = *(const bf16x8*)(Mbf + (size_t)(ob + ni * 16 + l15) * 256 + k0 + quad * 8);
                acc[0][ni] = __builtin_amdgcn_mfma_f32_16x16x32_bf16(a[0], bb, acc[0][ni], 0, 0, 0);
                acc[1][ni] = __builtin_amdgcn_mfma_f32_16x16x32_bf16(a[1], bb, acc[1][ni], 0, 0, 0);
            }
        }
        #pragma unroll
        for (int ni = 0; ni < 8; ++ni){
            int o = ob + ni * 16 + l15;
            float dv = dvec[o];
            #pragma unroll
            for (int mi = 0; mi < 2; ++mi){
                int nrow = nb + mi * 16 + quad * 4;
                #pragma unroll
                for (int r = 0; r < 4; ++r){
                    int node = nrow + r;
                    if (node < N_NODES) c[(size_t)node * 256 + o] = (__bf16)(acc[mi][ni][r] + dv);
                }
            }
        }
    } else {
        // ----- EDGE path -----
        int eid = b - b / 5 - 1;
        if (t == 0) s_is64 = 1;
        __syncthreads();
        unsigned v = ((const unsigned*)row_raw)[2 * t + 1] | ((const unsigned*)col_raw)[2 * t + 1];
        if (v) s_is64 = 0;
        __syncthreads();

        int e = eid * 256 + t;
        if (e >= N_EDGES) return;
        int r, cl;
        if (s_is64){
            r  = (int)((const long long*)row_raw)[e];
            cl = (int)((const long long*)col_raw)[e];
        } else {
            r  = ((const int*)row_raw)[e];
            cl = ((const int*)col_raw)[e];
        }
        float4 pa = *(const float4*)(proj_a + (size_t)cl * 4);
        float4 pb = *(const float4*)(proj_b + (size_t)r * 4);
        float h1[4];
        h1[0] = pa.x + pb.x + asg_b1[0];
        h1[1] = pa.y + pb.y + asg_b1[1];
        h1[2] = pa.z + pb.z + asg_b1[2];
        h1[3] = pa.w + pb.w + asg_b1[3];
        float h2[4];
        #pragma unroll
        for (int i = 0; i < 4; ++i){
            float s = asg_b2[i];
            #pragma unroll
            for (int j = 0; j < 4; ++j) s += asg_W2[i * 4 + j] * h1[j];
            h2[i] = s;
        }
        float m = fmaxf(fmaxf(h2[0], h2[1]), fmaxf(h2[2], h2[3]));
        float e0 = __expf(h2[0] - m), e1 = __expf(h2[1] - m);
        float e2 = __expf(h2[2] - m), e3 = __expf(h2[3] - m);
        float inv = 1.f / (e0 + e1 + e2 + e3);
        unsigned b0 = f2bf(e0 * inv), b1 = f2bf(e1 * inv);
        unsigned b2 = f2bf(e2 * inv), b3 = f2bf(e3 * inv);
        int4 rec;
        rec.x = cl;
        rec.y = (int)(b0 | (b1 << 16));
        rec.z = (int)(b2 | (b3 << 16));
        rec.w = 0;
        int pos = atomicAdd(&deg[r], 1);
        if (pos < BCAP) bucket[(size_t)r * BCAP + pos] = rec;
    }
}

// ---- K_node v2: ONE WAVE PER NODE. Zero barriers, zero LDS.
__global__ __launch_bounds__(256) void k_node(const __bf16* __restrict__ c,
                                              const int* __restrict__ deg,
                                              const int4* __restrict__ bucket,
                                              const float* __restrict__ bias,
                                              const float* __restrict__ cls_W,
                                              const float* __restrict__ cls_b,
                                              float* __restrict__ out_h,
                                              float* __restrict__ out_logits){
    int wv = __builtin_amdgcn_readfirstlane((int)(threadIdx.x >> 6));
    int l  = threadIdx.x & 63;
    int n  = blockIdx.x * 4 + wv;
    int k2 = l >> 4;

    // per-lane constants (L1/L2-resident)
    float4 bi = *(const float4*)(bias  + l * 4);
    float4 w0 = *(const float4*)(cls_W + 0 * 256 + l * 4);
    float4 w1 = *(const float4*)(cls_W + 1 * 256 + l * 4);
    float4 w2 = *(const float4*)(cls_W + 2 * 256 + l * 4);
    float4 w3 = *(const float4*)(cls_W + 3 * 256 + l * 4);

    int dn = deg[n]; if (dn > BCAP) dn = BCAP;
    const int4* rec = bucket + (size_t)n * BCAP;
    const __bf16* cb = c + (size_t)l * 4;

    bool hi2 = (k2 & 2) != 0;    // use rec.z (k=2,3) vs rec.y (k=0,1)
    bool odd = (k2 & 1) != 0;    // use hi16 vs lo16

    float a0 = 0.f, a1 = 0.f, a2 = 0.f, a3 = 0.f;
    #pragma unroll 4
    for (int i = 0; i < dn; ++i){
        int4 rc = rec[i];                         // wave-uniform -> s_load
        int  ww = hi2 ? rc.z : rc.y;
        unsigned wb = odd ? ((unsigned)ww & 0xffff0000u) : ((unsigned)ww << 16);
        float w = bits2f(wb);
        uint2 vv = *(const uint2*)(cb + (size_t)rc.x * 256);   // 8B/lane, 512B/wave
        a0 += w * bits2f(vv.x << 16);
        a1 += w * bits2f(vv.x & 0xffff0000u);
        a2 += w * bits2f(vv.y << 16);
        a3 += w * bits2f(vv.y & 0xffff0000u);
    }
    a0 += bi.x; a1 += bi.y; a2 += bi.z; a3 += bi.w;

    // norm over each 64-feature group = 16 consecutive lanes
    float ss = a0 * a0 + a1 * a1 + a2 * a2 + a3 * a3;
    ss += __shfl_xor(ss, 1);
    ss += __shfl_xor(ss, 2);
    ss += __shfl_xor(ss, 4);
    ss += __shfl_xor(ss, 8);
    float nrm = fmaxf(sqrtf(ss), EPS);
    float h0 = a0 / nrm, h1 = a1 / nrm, h2 = a2 / nrm, h3 = a3 / nrm;
    *(float4*)(out_h + (size_t)n * 256 + l * 4) = make_float4(h0, h1, h2, h3);

    // logits: per-lane partial dot then full-wave butterfly
    float p0 = h0 * w0.x + h1 * w0.y + h2 * w0.z + h3 * w0.w;
    float p1 = h0 * w1.x + h1 * w1.y + h2 * w1.z + h3 * w1.w;
    float p2 = h0 * w2.x + h1 * w2.y + h2 * w2.z + h3 * w2.w;
    float p3 = h0 * w3.x + h1 * w3.y + h2 * w3.z + h3 * w3.w;
    #pragma unroll
    for (int off = 1; off < 64; off <<= 1){
        p0 += __shfl_xor(p0, off);
        p1 += __shfl_xor(p1, off);
        p2 += __shfl_xor(p2, off);
        p3 += __shfl_xor(p3, off);
    }
    if (l == 0){
        float4 lg = make_float4(p0 + cls_b[0], p1 + cls_b[1],
                                p2 + cls_b[2], p3 + cls_b[3]);
        *(float4*)(out_logits + (size_t)n * 4) = lg;
    }
}

extern "C" void kernel_launch(void* const* d_in, const int* in_sizes, int n_in,
                              void* d_out, int out_size, void* d_ws, size_t ws_size,
                              hipStream_t stream){
    const float* x       = (const float*)d_in[0];
    const void*  row_raw = d_in[1];
    const void*  col_raw = d_in[2];
    const float* asg_W1  = (const float*)d_in[3];
    const float* asg_b1  = (const float*)d_in[4];
    const float* asg_W2  = (const float*)d_in[5];
    const float* asg_b2  = (const float*)d_in[6];
    const float* lin_W   = (const float*)d_in[7];
    const float* lin_b   = (const float*)d_in[8];
    const float* conv_W  = (const float*)d_in[9];
    const float* bias    = (const float*)d_in[10];
    const float* cls_W   = (const float*)d_in[11];
    const float* cls_b   = (const float*)d_in[12];

    char* ws = (char*)d_ws;
    size_t off = 0;
    auto alloc = [&](size_t bytes) -> void* {
        void* p = ws + off;
        off += (bytes + 255) & ~(size_t)255;
        return p;
    };
    __bf16* c      = (__bf16*)alloc((size_t)N_NODES * 256 * 2);       // 51.2 MB
    int4*   bucket = (int4*)alloc((size_t)N_NODES * BCAP * 16);       // 102.4 MB
    float*  proj_a = (float*)alloc((size_t)N_NODES * 4 * 4);
    float*  proj_b = (float*)alloc((size_t)N_NODES * 4 * 4);
    __bf16* Mbf    = (__bf16*)alloc(65536 * 2);
    float*  dvec   = (float*)alloc(256 * 4);
    int*    deg    = (int*)alloc((size_t)N_NODES * 4);

    float* out_h = (float*)d_out;
    float* out_l = out_h + (size_t)N_NODES * 256;

    hipLaunchKernelGGL(k_init, dim3(647 + (N_NODES + 127) / 128), dim3(256), 0, stream,
                       deg, lin_W, lin_b, conv_W, Mbf, dvec, asg_W1, x, proj_a, proj_b);
    hipLaunchKernelGGL(k_ge, dim3(7813), dim3(256), 0, stream,
                       x, (const __bf16*)Mbf, dvec, c,
                       row_raw, col_raw, proj_a, proj_b, asg_b1, asg_W2, asg_b2,
                       deg, bucket);
    hipLaunchKernelGGL(k_node, dim3(N_NODES / 4), dim3(256), 0, stream,
                       c, deg, bucket, bias, cls_W, cls_b, out_h, out_l);
}

// Round 15
// 460.666 us; speedup vs baseline: 1.1194x; 1.0785x over previous
//
#include <hip/hip_runtime.h>
#include <hip/hip_bf16.h>

#define N_NODES 100000
#define N_EDGES 1600000
#define BCAP    64          // bucket capacity per node (max degree; Poisson(16) tail ~1e-20)
#define EPS     1e-12f

typedef __bf16 bf16x8 __attribute__((ext_vector_type(8)));
typedef float  f32x4  __attribute__((ext_vector_type(4)));

__device__ __forceinline__ unsigned short f2bf(float f){
    union { float f; unsigned int i; } v; v.f = f;
    unsigned int x = v.i;
    return (unsigned short)((x + 0x7fffu + ((x >> 16) & 1u)) >> 16);
}
__device__ __forceinline__ float bits2f(unsigned int u){
    union { unsigned int i; float f; } v; v.i = u; return v.f;
}

// ---- K_init: [0,390] zero deg; [391,646] fuse M/dvec (PACKED layout); [647,1428] proj
// Mp packed fragment-contiguous: element (o,f) -> tile(o>>4), step(f>>5),
// lane(quad(f)*16 + (o&15)), elem(f&7). A wave's 16B-fragment reads are contiguous.
__global__ void k_init(int* __restrict__ deg,
                       const float* __restrict__ lin_W,
                       const float* __restrict__ lin_b,
                       const float* __restrict__ conv_W,
                       __bf16* __restrict__ Mp,
                       float* __restrict__ dvec,
                       const float* __restrict__ asg_W1,
                       const float* __restrict__ x,
                       float* __restrict__ proj_a,
                       float* __restrict__ proj_b){
    int b = blockIdx.x;
    int t = threadIdx.x;
    if (b < 391){
        int i = b * 256 + t;
        if (i < N_NODES) deg[i] = 0;
    } else if (b < 647){
        int id = (b - 391) * 256 + t;             // 0..65535
        int f  = id & 255;
        int o  = id >> 8;                          // k*64+q
        int k  = o >> 6;
        const float* cw = conv_W + o * 64;         // conv_W[k][q][p]
        const float* lw = lin_W + k * 64 * 256 + f;// lin_W[k][p][f]
        float s = 0.f;
        #pragma unroll 8
        for (int p = 0; p < 64; ++p) s += cw[p] * lw[p * 256];
        // packed write: tile = o>>4, step = f>>5, lane = ((f>>3)&3)*16 + (o&15), e = f&7
        size_t idx = ((((size_t)(o >> 4) * 8 + (f >> 5)) * 64) + ((f >> 3) & 3) * 16 + (o & 15)) * 8 + (f & 7);
        Mp[idx] = (__bf16)s;
        if (f == 0){
            const float* lb = lin_b + k * 64;
            float d = 0.f;
            for (int p = 0; p < 64; ++p) d += lb[p] * cw[p];
            dvec[o] = d;
        }
    } else {
        // ---- proj path: block = 128 nodes, 4 waves x 32 nodes, MFMA GEMV ----
        int p = b - 647;
        int lane = t & 63, wv = t >> 6;
        int nb = p * 128 + wv * 32;
        int l15 = lane & 15, quad = lane >> 4;
        f32x4 accp[2];
        accp[0] = f32x4{0.f, 0.f, 0.f, 0.f};
        accp[1] = f32x4{0.f, 0.f, 0.f, 0.f};
        const float* xg[2];
        #pragma unroll
        for (int mi = 0; mi < 2; ++mi){
            int row = nb + mi * 16 + l15;
            if (row >= N_NODES) row = N_NODES - 1;
            xg[mi] = x + (size_t)row * 256 + quad * 8;
        }
        const float* wrow = asg_W1;                // dummy base for l15>=8
        if (l15 < 4)      wrow = asg_W1 + l15 * 512;
        else if (l15 < 8) wrow = asg_W1 + (l15 - 4) * 512 + 256;
        bool wz = (l15 >= 8);
        for (int k0 = 0; k0 < 256; k0 += 32){
            bf16x8 a[2];
            #pragma unroll
            for (int mi = 0; mi < 2; ++mi){
                float4 lo = *(const float4*)(xg[mi] + k0);
                float4 hi = *(const float4*)(xg[mi] + k0 + 4);
                a[mi][0] = (__bf16)lo.x; a[mi][1] = (__bf16)lo.y;
                a[mi][2] = (__bf16)lo.z; a[mi][3] = (__bf16)lo.w;
                a[mi][4] = (__bf16)hi.x; a[mi][5] = (__bf16)hi.y;
                a[mi][6] = (__bf16)hi.z; a[mi][7] = (__bf16)hi.w;
            }
            bf16x8 bw;
            if (!wz){
                float4 lo = *(const float4*)(wrow + k0 + quad * 8);
                float4 hi = *(const float4*)(wrow + k0 + quad * 8 + 4);
                bw[0] = (__bf16)lo.x; bw[1] = (__bf16)lo.y;
                bw[2] = (__bf16)lo.z; bw[3] = (__bf16)lo.w;
                bw[4] = (__bf16)hi.x; bw[5] = (__bf16)hi.y;
                bw[6] = (__bf16)hi.z; bw[7] = (__bf16)hi.w;
            } else {
                bw[0] = (__bf16)0.f; bw[1] = (__bf16)0.f; bw[2] = (__bf16)0.f; bw[3] = (__bf16)0.f;
                bw[4] = (__bf16)0.f; bw[5] = (__bf16)0.f; bw[6] = (__bf16)0.f; bw[7] = (__bf16)0.f;
            }
            accp[0] = __builtin_amdgcn_mfma_f32_16x16x32_bf16(a[0], bw, accp[0], 0, 0, 0);
            accp[1] = __builtin_amdgcn_mfma_f32_16x16x32_bf16(a[1], bw, accp[1], 0, 0, 0);
        }
        if (l15 < 8){
            #pragma unroll
            for (int mi = 0; mi < 2; ++mi){
                int nrow = nb + mi * 16 + quad * 4;
                #pragma unroll
                for (int r = 0; r < 4; ++r){
                    int node = nrow + r;
                    if (node < N_NODES){
                        float v = accp[mi][r];
                        if (l15 < 4) proj_a[node * 4 + l15] = v;
                        else         proj_b[node * 4 + (l15 - 4)] = v;
                    }
                }
            }
        }
    }
}

// ---- K_ge: fused GEMM+edge. GEMM path: LDS-staged A (dbuf, async-split stage),
// packed contiguous B loads. Edge path unchanged.
#define ASTRIDE 40   // bf16 elems per LDS row: 80 B = 5x16B aligned, 2-way banks max
__global__ __launch_bounds__(256, 4) void k_ge(const float* __restrict__ x,
                                               const __bf16* __restrict__ Mp,
                                               const float* __restrict__ dvec,
                                               __bf16* __restrict__ c,
                                               const void* __restrict__ row_raw,
                                               const void* __restrict__ col_raw,
                                               const float* __restrict__ proj_a,
                                               const float* __restrict__ proj_b,
                                               const float* __restrict__ asg_b1,
                                               const float* __restrict__ asg_W2,
                                               const float* __restrict__ asg_b2,
                                               int* __restrict__ deg,
                                               int4* __restrict__ bucket){
    __shared__ __align__(16) __bf16 sA[2][64][ASTRIDE];
    __shared__ int s_is64;
    int b = blockIdx.x;
    int t = threadIdx.x;
    if (b % 5 == 0){
        // ----- GEMM path: 64 nodes/block, waves (wm,wn); wave = 32n x 128o -----
        int gid = b / 5;
        int lane = t & 63, wv = t >> 6;
        int wm = wv & 1, wn = wv >> 1;
        int nb = gid * 64;
        int l15 = lane & 15, quad = lane >> 4;
        f32x4 acc[2][8];
        #pragma unroll
        for (int mi = 0; mi < 2; ++mi)
            #pragma unroll
            for (int ni = 0; ni < 8; ++ni) acc[mi][ni] = f32x4{0.f, 0.f, 0.f, 0.f};
        // staging role: thread t -> row t>>2, col-group t&3 (8 floats)
        int srow = t >> 2, scg = t & 3;
        int grow = nb + srow; if (grow >= N_NODES) grow = N_NODES - 1;
        const float* gx = x + (size_t)grow * 256 + scg * 8;
        // prologue: stage k-step 0
        {
            float4 lo = *(const float4*)(gx);
            float4 hi = *(const float4*)(gx + 4);
            bf16x8 v;
            v[0] = (__bf16)lo.x; v[1] = (__bf16)lo.y; v[2] = (__bf16)lo.z; v[3] = (__bf16)lo.w;
            v[4] = (__bf16)hi.x; v[5] = (__bf16)hi.y; v[6] = (__bf16)hi.z; v[7] = (__bf16)hi.w;
            *(bf16x8*)(&sA[0][srow][scg * 8]) = v;
        }
        __syncthreads();
        const __bf16* bbase = Mp + ((size_t)(wn * 8) * 8) * 512 + lane * 8;
        int p = 0;
        for (int ks = 0; ks < 8; ++ks){
            float4 nlo, nhi;
            bool pf = (ks < 7);
            if (pf){                                   // issue next-tile loads EARLY
                nlo = *(const float4*)(gx + (ks + 1) * 32);
                nhi = *(const float4*)(gx + (ks + 1) * 32 + 4);
            }
            bf16x8 a[2];
            a[0] = *(const bf16x8*)(&sA[p][wm * 32 + l15][quad * 8]);
            a[1] = *(const bf16x8*)(&sA[p][wm * 32 + 16 + l15][quad * 8]);
            #pragma unroll
            for (int ni = 0; ni < 8; ++ni){
                bf16x8 bb = *(const bf16x8*)(bbase + ((size_t)ni * 8 + ks) * 512);
                acc[0][ni] = __builtin_amdgcn_mfma_f32_16x16x32_bf16(a[0], bb, acc[0][ni], 0, 0, 0);
                acc[1][ni] = __builtin_amdgcn_mfma_f32_16x16x32_bf16(a[1], bb, acc[1][ni], 0, 0, 0);
            }
            if (pf){                                   // write staged tile LATE
                bf16x8 v;
                v[0] = (__bf16)nlo.x; v[1] = (__bf16)nlo.y; v[2] = (__bf16)nlo.z; v[3] = (__bf16)nlo.w;
                v[4] = (__bf16)nhi.x; v[5] = (__bf16)nhi.y; v[6] = (__bf16)nhi.z; v[7] = (__bf16)nhi.w;
                *(bf16x8*)(&sA[p ^ 1][srow][scg * 8]) = v;
            }
            __syncthreads();
            p ^= 1;
        }
        #pragma unroll
        for (int ni = 0; ni < 8; ++ni){
            int o = wn * 128 + ni * 16 + l15;
            float dv = dvec[o];
            #pragma unroll
            for (int mi = 0; mi < 2; ++mi){
                int nrow = nb + wm * 32 + mi * 16 + quad * 4;
                #pragma unroll
                for (int r = 0; r < 4; ++r){
                    int node = nrow + r;
                    if (node < N_NODES) c[(size_t)node * 256 + o] = (__bf16)(acc[mi][ni][r] + dv);
                }
            }
        }
    } else {
        // ----- EDGE path -----
        int eid = b - b / 5 - 1;
        if (t == 0) s_is64 = 1;
        __syncthreads();
        unsigned v = ((const unsigned*)row_raw)[2 * t + 1] | ((const unsigned*)col_raw)[2 * t + 1];
        if (v) s_is64 = 0;
        __syncthreads();

        int e = eid * 256 + t;
        if (e >= N_EDGES) return;
        int r, cl;
        if (s_is64){
            r  = (int)((const long long*)row_raw)[e];
            cl = (int)((const long long*)col_raw)[e];
        } else {
            r  = ((const int*)row_raw)[e];
            cl = ((const int*)col_raw)[e];
        }
        float4 pa = *(const float4*)(proj_a + (size_t)cl * 4);
        float4 pb = *(const float4*)(proj_b + (size_t)r * 4);
        float h1[4];
        h1[0] = pa.x + pb.x + asg_b1[0];
        h1[1] = pa.y + pb.y + asg_b1[1];
        h1[2] = pa.z + pb.z + asg_b1[2];
        h1[3] = pa.w + pb.w + asg_b1[3];
        float h2[4];
        #pragma unroll
        for (int i = 0; i < 4; ++i){
            float s = asg_b2[i];
            #pragma unroll
            for (int j = 0; j < 4; ++j) s += asg_W2[i * 4 + j] * h1[j];
            h2[i] = s;
        }
        float m = fmaxf(fmaxf(h2[0], h2[1]), fmaxf(h2[2], h2[3]));
        float e0 = __expf(h2[0] - m), e1 = __expf(h2[1] - m);
        float e2 = __expf(h2[2] - m), e3 = __expf(h2[3] - m);
        float inv = 1.f / (e0 + e1 + e2 + e3);
        unsigned b0 = f2bf(e0 * inv), b1 = f2bf(e1 * inv);
        unsigned b2 = f2bf(e2 * inv), b3 = f2bf(e3 * inv);
        int4 rec;
        rec.x = cl;
        rec.y = (int)(b0 | (b1 << 16));
        rec.z = (int)(b2 | (b3 << 16));
        rec.w = 0;
        int pos = atomicAdd(&deg[r], 1);
        if (pos < BCAP) bucket[(size_t)r * BCAP + pos] = rec;
    }
}

// ---- K_node v2: ONE WAVE PER NODE. Zero barriers, zero LDS.
__global__ __launch_bounds__(256) void k_node(const __bf16* __restrict__ c,
                                              const int* __restrict__ deg,
                                              const int4* __restrict__ bucket,
                                              const float* __restrict__ bias,
                                              const float* __restrict__ cls_W,
                                              const float* __restrict__ cls_b,
                                              float* __restrict__ out_h,
                                              float* __restrict__ out_logits){
    int wv = __builtin_amdgcn_readfirstlane((int)(threadIdx.x >> 6));
    int l  = threadIdx.x & 63;
    int n  = blockIdx.x * 4 + wv;
    int k2 = l >> 4;

    float4 bi = *(const float4*)(bias  + l * 4);
    float4 w0 = *(const float4*)(cls_W + 0 * 256 + l * 4);
    float4 w1 = *(const float4*)(cls_W + 1 * 256 + l * 4);
    float4 w2 = *(const float4*)(cls_W + 2 * 256 + l * 4);
    float4 w3 = *(const float4*)(cls_W + 3 * 256 + l * 4);

    int dn = deg[n]; if (dn > BCAP) dn = BCAP;
    const int4* rec = bucket + (size_t)n * BCAP;
    const __bf16* cb = c + (size_t)l * 4;

    bool hi2 = (k2 & 2) != 0;
    bool odd = (k2 & 1) != 0;

    float a0 = 0.f, a1 = 0.f, a2 = 0.f, a3 = 0.f;
    #pragma unroll 4
    for (int i = 0; i < dn; ++i){
        int4 rc = rec[i];
        int  ww = hi2 ? rc.z : rc.y;
        unsigned wb = odd ? ((unsigned)ww & 0xffff0000u) : ((unsigned)ww << 16);
        float w = bits2f(wb);
        uint2 vv = *(const uint2*)(cb + (size_t)rc.x * 256);
        a0 += w * bits2f(vv.x << 16);
        a1 += w * bits2f(vv.x & 0xffff0000u);
        a2 += w * bits2f(vv.y << 16);
        a3 += w * bits2f(vv.y & 0xffff0000u);
    }
    a0 += bi.x; a1 += bi.y; a2 += bi.z; a3 += bi.w;

    float ss = a0 * a0 + a1 * a1 + a2 * a2 + a3 * a3;
    ss += __shfl_xor(ss, 1);
    ss += __shfl_xor(ss, 2);
    ss += __shfl_xor(ss, 4);
    ss += __shfl_xor(ss, 8);
    float nrm = fmaxf(sqrtf(ss), EPS);
    float h0 = a0 / nrm, h1 = a1 / nrm, h2 = a2 / nrm, h3 = a3 / nrm;
    *(float4*)(out_h + (size_t)n * 256 + l * 4) = make_float4(h0, h1, h2, h3);

    float p0 = h0 * w0.x + h1 * w0.y + h2 * w0.z + h3 * w0.w;
    float p1 = h0 * w1.x + h1 * w1.y + h2 * w1.z + h3 * w1.w;
    float p2 = h0 * w2.x + h1 * w2.y + h2 * w2.z + h3 * w2.w;
    float p3 = h0 * w3.x + h1 * w3.y + h2 * w3.z + h3 * w3.w;
    #pragma unroll
    for (int off = 1; off < 64; off <<= 1){
        p0 += __shfl_xor(p0, off);
        p1 += __shfl_xor(p1, off);
        p2 += __shfl_xor(p2, off);
        p3 += __shfl_xor(p3, off);
    }
    if (l == 0){
        float4 lg = make_float4(p0 + cls_b[0], p1 + cls_b[1],
                                p2 + cls_b[2], p3 + cls_b[3]);
        *(float4*)(out_logits + (size_t)n * 4) = lg;
    }
}

extern "C" void kernel_launch(void* const* d_in, const int* in_sizes, int n_in,
                              void* d_out, int out_size, void* d_ws, size_t ws_size,
                              hipStream_t stream){
    const float* x       = (const float*)d_in[0];
    const void*  row_raw = d_in[1];
    const void*  col_raw = d_in[2];
    const float* asg_W1  = (const float*)d_in[3];
    const float* asg_b1  = (const float*)d_in[4];
    const float* asg_W2  = (const float*)d_in[5];
    const float* asg_b2  = (const float*)d_in[6];
    const float* lin_W   = (const float*)d_in[7];
    const float* lin_b   = (const float*)d_in[8];
    const float* conv_W  = (const float*)d_in[9];
    const float* bias    = (const float*)d_in[10];
    const float* cls_W   = (const float*)d_in[11];
    const float* cls_b   = (const float*)d_in[12];

    char* ws = (char*)d_ws;
    size_t off = 0;
    auto alloc = [&](size_t bytes) -> void* {
        void* p = ws + off;
        off += (bytes + 255) & ~(size_t)255;
        return p;
    };
    __bf16* c      = (__bf16*)alloc((size_t)N_NODES * 256 * 2);       // 51.2 MB
    int4*   bucket = (int4*)alloc((size_t)N_NODES * BCAP * 16);       // 102.4 MB
    float*  proj_a = (float*)alloc((size_t)N_NODES * 4 * 4);
    float*  proj_b = (float*)alloc((size_t)N_NODES * 4 * 4);
    __bf16* Mp     = (__bf16*)alloc(65536 * 2);
    float*  dvec   = (float*)alloc(256 * 4);
    int*    deg    = (int*)alloc((size_t)N_NODES * 4);

    float* out_h = (float*)d_out;
    float* out_l = out_h + (size_t)N_NODES * 256;

    hipLaunchKernelGGL(k_init, dim3(647 + (N_NODES + 127) / 128), dim3(256), 0, stream,
                       deg, lin_W, lin_b, conv_W, Mp, dvec, asg_W1, x, proj_a, proj_b);
    hipLaunchKernelGGL(k_ge, dim3(7813), dim3(256), 0, stream,
                       x, (const __bf16*)Mp, dvec, c,
                       row_raw, col_raw, proj_a, proj_b, asg_b1, asg_W2, asg_b2,
                       deg, bucket);
    hipLaunchKernelGGL(k_node, dim3(N_NODES / 4), dim3(256), 0, stream,
                       c, deg, bucket, bias, cls_W, cls_b, out_h, out_l);
}